// Round 7
// baseline (177.290 us; speedup 1.0000x reference)
//
#include <hip/hip_runtime.h>
#include <cstdint>
#include <cstddef>

#define BB 16
#define CC 256
#define NP 1024   // H*W

typedef __attribute__((ext_vector_type(8))) short bf16x8;
typedef __attribute__((ext_vector_type(4))) float f32x4;
typedef unsigned short u16;

__device__ __forceinline__ u16 f2bf(float f) {
    union { float f; uint32_t u; } v; v.f = f;
    uint32_t u = v.u;
    return (u16)((u + 0x7FFFu + ((u >> 16) & 1u)) >> 16);   // RNE
}

// ---------------- SE mean (blocks 0..4095) + weight convert (blocks 4096..4607) ----------------
__global__ __launch_bounds__(256)
void se_mean_conv_kernel(const float* __restrict__ x, float* __restrict__ s_mean,
                         const float* __restrict__ w1, u16* __restrict__ d1,
                         const float* __restrict__ w2, u16* __restrict__ d2) {
    int blk = blockIdx.x;
    int t = threadIdx.x;
    if (blk < BB * CC) {
        const float* p = x + (size_t)blk * NP;
        float4 v = *(const float4*)(p + t * 4);
        float s = (v.x + v.y) + (v.z + v.w);
#pragma unroll
        for (int off = 32; off; off >>= 1) s += __shfl_down(s, off, 64);
        __shared__ float red[4];
        if ((t & 63) == 0) red[t >> 6] = s;
        __syncthreads();
        if (t == 0) s_mean[blk] = (red[0] + red[1] + red[2] + red[3]) * (1.0f / NP);
    } else {
        int blk2 = blk - BB * CC;
        const float* src = (blk2 < 256) ? w1 : w2;
        u16* dst = (blk2 < 256) ? d1 : d2;
        int i = ((blk2 & 255) * 256 + t) * 4;
        float4 v = *(const float4*)(src + i);
        ushort4 o;
        o.x = f2bf(v.x); o.y = f2bf(v.y); o.z = f2bf(v.z); o.w = f2bf(v.w);
        *(ushort4*)(dst + i) = o;
    }
}

// ---------------- SE MLP: sigmoid scales, once per batch (grid = BB) ----------------
__global__ __launch_bounds__(256)
void se_mlp_kernel(const float* __restrict__ s_mean,
                   const float* __restrict__ fc1_w, const float* __restrict__ fc1_b,
                   const float* __restrict__ fc2_w, const float* __restrict__ fc2_b,
                   float* __restrict__ sig) {
    int b = blockIdx.x, t = threadIdx.x;
    __shared__ float sm[256];
    __shared__ float part[4][64];
    __shared__ float h1[64];
    sm[t] = s_mean[b * 256 + t];
    __syncthreads();
    int to = t & 63, g = t >> 6;
    float a = 0.f;
#pragma unroll 8
    for (int c = 0; c < 64; ++c) a += fc1_w[to * 256 + g * 64 + c] * sm[g * 64 + c];
    part[g][to] = a;
    __syncthreads();
    if (t < 64) h1[t] = fmaxf(part[0][t] + part[1][t] + part[2][t] + part[3][t] + fc1_b[t], 0.f);
    __syncthreads();
    float acc = fc2_b[t];
#pragma unroll 8
    for (int j = 0; j < 64; ++j) acc += fc2_w[t * 64 + j] * h1[j];
    sig[b * 256 + t] = 1.f / (1.f + __expf(-acc));
}

// ---- scale + transpose (+ fused qkv on ct==0 blocks); SE scales precomputed ----
__global__ __launch_bounds__(256)
void scale_transpose_qkv_kernel(const float* __restrict__ x, const float* __restrict__ sig,
                                const float* __restrict__ qW, const float* __restrict__ qB,
                                u16* __restrict__ ygt, u16* __restrict__ Qt,
                                u16* __restrict__ Kt, u16* __restrict__ Vb) {
    // grid: (16 nt, 4 ct, BB)
    int nt = blockIdx.x, ct = blockIdx.y, b = blockIdx.z;
    __shared__ float tile[64][65];
    __shared__ float ws[64 * 32];
    __shared__ float bs[64];
    __shared__ float vtile[32][64];
    __shared__ float sig_l[64];
    int t = threadIdx.x;
    const float* Xb = x + ((size_t)b * CC + ct * 64) * NP + nt * 64;
    if (t < 64) sig_l[t] = sig[b * 256 + ct * 64 + t];
    if (ct == 0) {
        for (int e = t; e < 2048; e += 256) ws[e] = qW[e];
        if (t < 64) bs[t] = qB[t];
    }
#pragma unroll
    for (int p = 0; p < 4; ++p) {
        int e = t + p * 256;
        int c = e >> 4, n4 = (e & 15) * 4;
        float4 v = *(const float4*)&Xb[(size_t)c * NP + n4];
        tile[c][n4] = v.x; tile[c][n4 + 1] = v.y; tile[c][n4 + 2] = v.z; tile[c][n4 + 3] = v.w;
    }
    __syncthreads();
    u16* Yb = ygt + ((size_t)b * NP + nt * 64) * CC + ct * 64;
#pragma unroll
    for (int p = 0; p < 4; ++p) {
        int e = t + p * 256;
        int n = e >> 4, c4 = (e & 15) * 4;
        if (ct * 64 + c4 >= 32) {
            ushort4 o;
            o.x = f2bf(tile[c4][n] * sig_l[c4]);
            o.y = f2bf(tile[c4 + 1][n] * sig_l[c4 + 1]);
            o.z = f2bf(tile[c4 + 2][n] * sig_l[c4 + 2]);
            o.w = f2bf(tile[c4 + 3][n] * sig_l[c4 + 3]);
            *(ushort4*)&Yb[(size_t)n * CC + c4] = o;
        }
    }
    if (ct == 0) {
        int nn = t & 63, g = t >> 6;
        int n = nt * 64 + nn;
        float xs[32];
#pragma unroll
        for (int c = 0; c < 32; ++c) xs[c] = tile[c][nn] * sig_l[c];
        float acc[16];
#pragma unroll
        for (int oc = 0; oc < 16; ++oc) {
            int o = g * 16 + oc;
            float a = bs[o];
#pragma unroll
            for (int c = 0; c < 32; ++c) a += ws[o * 32 + c] * xs[c];
            acc[oc] = a;
        }
        if (g == 0) {
            u16* qr = Qt + ((size_t)b * NP + n) * 32;
            ushort4 z4; z4.x = 0; z4.y = 0; z4.z = 0; z4.w = 0;
#pragma unroll
            for (int j = 0; j < 16; j += 4) {
                ushort4 o4;
                o4.x = f2bf(acc[j] * 0.25f);     o4.y = f2bf(acc[j + 1] * 0.25f);
                o4.z = f2bf(acc[j + 2] * 0.25f); o4.w = f2bf(acc[j + 3] * 0.25f);
                *(ushort4*)&qr[j] = o4;
            }
            *(ushort4*)&qr[16] = z4; *(ushort4*)&qr[20] = z4;
            *(ushort4*)&qr[24] = z4; *(ushort4*)&qr[28] = z4;
        } else if (g == 1) {
            u16* kr = Kt + ((size_t)b * NP + n) * 32;
            ushort4 z4; z4.x = 0; z4.y = 0; z4.z = 0; z4.w = 0;
#pragma unroll
            for (int j = 0; j < 16; j += 4) {
                ushort4 k4;
                k4.x = f2bf(acc[j]);     k4.y = f2bf(acc[j + 1]);
                k4.z = f2bf(acc[j + 2]); k4.w = f2bf(acc[j + 3]);
                *(ushort4*)&kr[j] = k4;
            }
            *(ushort4*)&kr[16] = z4; *(ushort4*)&kr[20] = z4;
            *(ushort4*)&kr[24] = z4; *(ushort4*)&kr[28] = z4;
        } else {
#pragma unroll
            for (int oc = 0; oc < 16; ++oc) vtile[(g - 2) * 16 + oc][nn] = acc[oc];
        }
        __syncthreads();
        for (int e = t; e < 2048; e += 256) {
            int c = e >> 6, nn2 = e & 63;
            Vb[(size_t)b * 32 * NP + (size_t)c * NP + nt * 64 + nn2] = f2bf(vtile[c][nn2]);
        }
    }
}

// ---------------- MFMA flash attention + fused proj (parallel epilogue) ----------------
__global__ __launch_bounds__(256)
void attn_mfma_kernel(const u16* __restrict__ Qt, const u16* __restrict__ Kt,
                      const u16* __restrict__ Vb,
                      const float* __restrict__ proj_w, const float* __restrict__ proj_b,
                      u16* __restrict__ ygt) {
    int b = blockIdx.x & 15;
    int n0 = (blockIdx.x >> 4) * 16;
    __shared__ __align__(16) u16 P_lds[4][16][40];
    __shared__ float al_lds[4][16];
    __shared__ float sm_lds[4][16];
    __shared__ float sl_lds[4][16];
    __shared__ float O_lds[4][16][33];
    __shared__ float pw_s[32][33];   // +1 pad: proj reads conflict-free
    __shared__ float pb_s[32];
    int t = threadIdx.x;
    int w = t >> 6, lane = t & 63;
    int q = lane >> 4, idx = lane & 15;

    for (int e = t; e < 1024; e += 256) pw_s[e >> 5][e & 31] = proj_w[e];
    if (t < 32) pb_s[t] = proj_b[t];
    __syncthreads();

    const u16* Qb = Qt + (size_t)b * NP * 32;
    const u16* Kb = Kt + (size_t)b * NP * 32;
    const u16* Vp = Vb + (size_t)b * 32 * NP;

    int nrow = n0 + idx;
    bf16x8 aq = *(const bf16x8*)&Qb[(size_t)nrow * 32 + q * 8];

    f32x4 O0 = {0.f, 0.f, 0.f, 0.f}, O1 = {0.f, 0.f, 0.f, 0.f};
    float m_run[4] = {-1e30f, -1e30f, -1e30f, -1e30f};
    float l_run[4] = {0.f, 0.f, 0.f, 0.f};

    int mbase = w * 256;
    for (int m0 = mbase; m0 < mbase + 256; m0 += 32) {
        bf16x8 bk0 = *(const bf16x8*)&Kb[(size_t)(m0 + idx) * 32 + q * 8];
        bf16x8 bk1 = *(const bf16x8*)&Kb[(size_t)(m0 + 16 + idx) * 32 + q * 8];
        bf16x8 va0 = *(const bf16x8*)&Vp[(size_t)idx * NP + m0 + q * 8];
        bf16x8 va1 = *(const bf16x8*)&Vp[(size_t)(16 + idx) * NP + m0 + q * 8];
        f32x4 z = {0.f, 0.f, 0.f, 0.f};
        f32x4 S0 = __builtin_amdgcn_mfma_f32_16x16x32_bf16(aq, bk0, z, 0, 0, 0);
        f32x4 S1 = __builtin_amdgcn_mfma_f32_16x16x32_bf16(aq, bk1, z, 0, 0, 0);
        float mx[4], p0[4], p1[4], alpha[4];
#pragma unroll
        for (int r = 0; r < 4; ++r) mx[r] = fmaxf(S0[r], S1[r]);
#pragma unroll
        for (int off = 1; off < 16; off <<= 1)
#pragma unroll
            for (int r = 0; r < 4; ++r) mx[r] = fmaxf(mx[r], __shfl_xor(mx[r], off, 64));
#pragma unroll
        for (int r = 0; r < 4; ++r) {
            float nm = fmaxf(m_run[r], mx[r]);
            alpha[r] = __expf(m_run[r] - nm);
            m_run[r] = nm;
            p0[r] = __expf(S0[r] - nm);
            p1[r] = __expf(S1[r] - nm);
        }
#pragma unroll
        for (int r = 0; r < 4; ++r) {
            float s = p0[r] + p1[r];
#pragma unroll
            for (int off = 1; off < 16; off <<= 1) s += __shfl_xor(s, off, 64);
            l_run[r] = l_run[r] * alpha[r] + s;
        }
#pragma unroll
        for (int r = 0; r < 4; ++r) {
            P_lds[w][q * 4 + r][idx]      = f2bf(p0[r]);
            P_lds[w][q * 4 + r][idx + 16] = f2bf(p1[r]);
        }
        if (idx == 0) {
#pragma unroll
            for (int r = 0; r < 4; ++r) al_lds[w][q * 4 + r] = alpha[r];
        }
        float an = al_lds[w][idx];
#pragma unroll
        for (int r = 0; r < 4; ++r) { O0[r] *= an; O1[r] *= an; }
        bf16x8 pf = *(const bf16x8*)&P_lds[w][idx][q * 8];
        O0 = __builtin_amdgcn_mfma_f32_16x16x32_bf16(va0, pf, O0, 0, 0, 0);
        O1 = __builtin_amdgcn_mfma_f32_16x16x32_bf16(va1, pf, O1, 0, 0, 0);
    }
    if (idx == 0) {
#pragma unroll
        for (int r = 0; r < 4; ++r) {
            sm_lds[w][q * 4 + r] = m_run[r];
            sl_lds[w][q * 4 + r] = l_run[r];
        }
    }
#pragma unroll
    for (int r = 0; r < 4; ++r) {
        O_lds[w][idx][q * 4 + r]      = O0[r];
        O_lds[w][idx][q * 4 + r + 16] = O1[r];
    }
    __syncthreads();

    // ---- Phase 1: combine 4 wave-partials (all 256 threads, 2 elements each) ----
#pragma unroll
    for (int p = 0; p < 2; ++p) {
        int el = t + p * 256;
        int row = el >> 5, col = el & 31;
        float m0_ = sm_lds[0][row], m1 = sm_lds[1][row], m2 = sm_lds[2][row], m3 = sm_lds[3][row];
        float gm = fmaxf(fmaxf(m0_, m1), fmaxf(m2, m3));
        float e0 = __expf(m0_ - gm), e1 = __expf(m1 - gm);
        float e2 = __expf(m2 - gm), e3 = __expf(m3 - gm);
        float linv = 1.f / (sl_lds[0][row] * e0 + sl_lds[1][row] * e1 +
                            sl_lds[2][row] * e2 + sl_lds[3][row] * e3);
        O_lds[0][row][col] = (O_lds[0][row][col] * e0 + O_lds[1][row][col] * e1 +
                              O_lds[2][row][col] * e2 + O_lds[3][row][col] * e3) * linv;
    }
    __syncthreads();

    // ---- Phase 2: proj across all 4 waves: wave w owns rows w*4..+4 ----
    {
        int row = (w << 2) + q;
        float o0 = pb_s[idx], o1 = pb_s[idx + 16];
#pragma unroll
        for (int c = 0; c < 32; ++c) {
            float xv = O_lds[0][row][c];
            o0 += pw_s[idx][c] * xv;
            o1 += pw_s[idx + 16][c] * xv;
        }
        u16* yrow = ygt + ((size_t)b * NP + n0 + row) * CC;
        yrow[idx]      = f2bf(o0);
        yrow[idx + 16] = f2bf(o1);
    }
}

// ---------------- Fused FFN v7: v3 skeleton + 2x reg-blocked stage1, single af buffer ----------------
// v3's barrier/DMA structure verbatim. Stage1 decomposition = v6 (4 m-groups x 2 n-halves,
// af[2][8] so each Ys ds_read feeds 2 MFMAs -> stage1 LDS reads halved). The v6 regression
// (afn double-buffer -> 210-VGPR live set -> scheduler sank the loads, VGPR=108) is fixed by
// deleting afn: af reloaded in place ONCE per iteration, placed after barrier B (drain window
// = stage2) and pinned with sched_barrier(0) so it cannot sink into the next stage1.
__global__ __launch_bounds__(512, 2)
void ffn_fused_kernel(const u16* __restrict__ w1b, const u16* __restrict__ w2b,
                      const u16* __restrict__ ygt,
                      const float* __restrict__ bias1, const float* __restrict__ bias2,
                      float* __restrict__ out) {
    __shared__ __align__(16) u16 Ys[4][64][64];     // 32 KB: y tile [kb][n][64k swz]
    __shared__ __align__(16) u16 Hs[2][64][64];     // 16 KB: h superchunk [hh][n][64m swz]
    __shared__ __align__(16) u16 W2s[2][256][64];   // 64 KB: W2 slice [hh][m2][64k swz]
    __shared__ float Bs1[1024];                     // 4 KB
    int t = threadIdx.x;
    int w = t >> 6, lane = t & 63;
    int q = lane >> 4, idx = lane & 15;
    int srow = lane >> 3;            // 0..7
    int gch = (lane & 7) ^ srow;     // pre-swizzled source chunk
    int n0 = blockIdx.x * 64;        // flat pixel base (b*1024 + n)
    int rot = blockIdx.x & 7;
    int hh = w >> 2, wm = w & 3;
    int nh = hh * 32;                // stage1 n-half base

#define ISSUE_W2S(sc_)                                                                     \
    {                                                                                      \
        _Pragma("unroll")                                                                  \
        for (int e = 0; e < 8; ++e) {                                                      \
            int hh2 = e >> 2, rnd = e & 3;                                                 \
            int rw = rnd * 64 + w * 8;                                                     \
            __builtin_amdgcn_global_load_lds(                                              \
                (const __attribute__((address_space(1))) void*)(w2b + (size_t)(rw + srow) * 1024 + (sc_) * 128 + hh2 * 64 + gch * 8), \
                (__attribute__((address_space(3))) void*)(&W2s[hh2][rw][0]),               \
                16, 0, 0);                                                                 \
        }                                                                                  \
    }

#define LOAD_AF(sc_)                                                                       \
    {                                                                                      \
        const u16* a1 = w1b + ((size_t)((sc_) * 128 + wm * 32 + idx)) * CC;                \
        _Pragma("unroll")                                                                  \
        for (int i2 = 0; i2 < 2; ++i2)                                                     \
            _Pragma("unroll")                                                              \
            for (int s = 0; s < 8; ++s)                                                    \
                af[i2][s] = *(const bf16x8*)(a1 + (size_t)i2 * 16 * CC + s * 32 + q * 8);  \
    }

    // stage Ys: 256 rows of 128 B, linear LDS dest + pre-swizzled source
#pragma unroll
    for (int e = 0; e < 4; ++e) {
        __builtin_amdgcn_global_load_lds(
            (const __attribute__((address_space(1))) void*)(ygt + (size_t)(n0 + w * 8 + srow) * CC + e * 64 + gch * 8),
            (__attribute__((address_space(3))) void*)(&Ys[e][w * 8][0]),
            16, 0, 0);
    }
    Bs1[t] = bias1[t];
    Bs1[t + 512] = bias1[t + 512];

    f32x4 oacc[4][4];
#pragma unroll
    for (int f = 0; f < 4; ++f)
#pragma unroll
        for (int j = 0; j < 4; ++j) { f32x4 z = {0.f, 0.f, 0.f, 0.f}; oacc[f][j] = z; }

    ISSUE_W2S(rot)
    bf16x8 af[2][8];
    LOAD_AF(rot)
    __syncthreads();   // drains Ys + W2s(first) + af

    for (int it = 0; it < 8; ++it) {
        int sc  = (it + rot) & 7;
        int scn = (it + 1 + rot) & 7;

        // stage 1: h[32m x 32n] per wave (rows wm*32..+32, cols nh..+32), K=256 from Ys
        f32x4 hacc[2][2];
#pragma unroll
        for (int i2 = 0; i2 < 2; ++i2)
#pragma unroll
            for (int j = 0; j < 2; ++j) { f32x4 z = {0.f, 0.f, 0.f, 0.f}; hacc[i2][j] = z; }
#pragma unroll
        for (int s = 0; s < 8; ++s) {
            int kb = s >> 1, h2 = s & 1;
#pragma unroll
            for (int j = 0; j < 2; ++j) {
                bf16x8 yb = *(const bf16x8*)&Ys[kb][nh + j * 16 + idx][(((q + 4 * h2) ^ (idx & 7)) * 8)];
                hacc[0][j] = __builtin_amdgcn_mfma_f32_16x16x32_bf16(af[0][s], yb, hacc[0][j], 0, 0, 0);
                hacc[1][j] = __builtin_amdgcn_mfma_f32_16x16x32_bf16(af[1][s], yb, hacc[1][j], 0, 0, 0);
            }
        }

        // bias + relu + pack -> Hs (layout identical to v3: chunk = (m>>3)^(n&7), pos = m&7)
#pragma unroll
        for (int i2 = 0; i2 < 2; ++i2) {
            int u = wm * 2 + i2;                         // 16-row group within superchunk
            int mb = sc * 128 + u * 16 + q * 4;
            float b0 = Bs1[mb], b1v = Bs1[mb + 1], b2v = Bs1[mb + 2], b3v = Bs1[mb + 3];
            int hh2 = u >> 2;                            // which 64-m half (Hs buffer)
            int g8 = (u & 3) * 2 + (q >> 1);             // m>>3 within the 64-m half
#pragma unroll
            for (int j = 0; j < 2; ++j) {
                int n = nh + j * 16 + idx;
                int chk = g8 ^ (n & 7);
                uint32_t lo = (uint32_t)f2bf(fmaxf(hacc[i2][j][0] + b0, 0.f)) |
                              ((uint32_t)f2bf(fmaxf(hacc[i2][j][1] + b1v, 0.f)) << 16);
                uint32_t hi = (uint32_t)f2bf(fmaxf(hacc[i2][j][2] + b2v, 0.f)) |
                              ((uint32_t)f2bf(fmaxf(hacc[i2][j][3] + b3v, 0.f)) << 16);
                uint32_t* hp = (uint32_t*)&Hs[hh2][n][chk * 8 + (q & 1) * 4];
                hp[0] = lo; hp[1] = hi;
            }
        }
        __syncthreads();   // B: Hs visible + W2s(sc) DMA drained

        // reload af for next superchunk; pinned so it issues HERE (drain window = stage2)
        if (it + 1 < 8) {
            LOAD_AF(scn)
            __builtin_amdgcn_sched_barrier(0);
        }

        // stage 2: oacc[64m2 x 64n] += W2s[hh] @ Hs[hh] (wave's own k-half) -- v3 verbatim
#pragma unroll
        for (int s2 = 0; s2 < 2; ++s2) {
            bf16x8 a2f[4];
#pragma unroll
            for (int f = 0; f < 4; ++f)
                a2f[f] = *(const bf16x8*)&W2s[hh][wm * 64 + f * 16 + idx][(((q + 4 * s2) ^ (idx & 7)) * 8)];
#pragma unroll
            for (int j = 0; j < 4; ++j) {
                bf16x8 hb = *(const bf16x8*)&Hs[hh][j * 16 + idx][(((q + 4 * s2) ^ (idx & 7)) * 8)];
#pragma unroll
                for (int f = 0; f < 4; ++f)
                    oacc[f][j] = __builtin_amdgcn_mfma_f32_16x16x32_bf16(a2f[f], hb, oacc[f][j], 0, 0, 0);
            }
        }
        __syncthreads();   // C: all waves done reading W2s/Hs -> safe to overwrite

        if (it + 1 < 8) ISSUE_W2S(scn)
    }
#undef ISSUE_W2S
#undef LOAD_AF

    // cross-pair reduction through the dead W2s region (64 KB = 4 pairs x 16 KB f32)
    float* R = (float*)&W2s[0][0][0];
    if (w >= 4) {
#pragma unroll
        for (int f = 0; f < 4; ++f)
#pragma unroll
            for (int j = 0; j < 4; ++j)
#pragma unroll
                for (int r = 0; r < 4; ++r)
                    R[(wm * 64 + f * 16 + q * 4 + r) * 64 + j * 16 + idx] = oacc[f][j][r];
    }
    __syncthreads();
    if (w < 4) {
        int b = n0 >> 10, nnb = n0 & 1023;
#pragma unroll
        for (int f = 0; f < 4; ++f) {
            int m2 = wm * 64 + f * 16 + q * 4;
            float c0 = bias2[m2], c1 = bias2[m2 + 1], c2 = bias2[m2 + 2], c3 = bias2[m2 + 3];
#pragma unroll
            for (int j = 0; j < 4; ++j) {
                int col = j * 16 + idx;
                const float* Rp = &R[m2 * 64 + col];
                float* p = out + ((size_t)b * CC + m2) * NP + nnb + col;
                f32x4 v = oacc[f][j];
                p[0]      = v.x + c0 + Rp[0];
                p[NP]     = v.y + c1 + Rp[64];
                p[2 * NP] = v.z + c2 + Rp[128];
                p[3 * NP] = v.w + c3 + Rp[192];
            }
        }
    }
}

extern "C" void kernel_launch(void* const* d_in, const int* in_sizes, int n_in,
                              void* d_out, int out_size, void* d_ws, size_t ws_size,
                              hipStream_t stream) {
    const float* x      = (const float*)d_in[0];
    const float* fc1_w  = (const float*)d_in[1];
    const float* fc1_b  = (const float*)d_in[2];
    const float* fc2_w  = (const float*)d_in[3];
    const float* fc2_b  = (const float*)d_in[4];
    const float* qkv_w  = (const float*)d_in[5];
    const float* qkv_b  = (const float*)d_in[6];
    const float* proj_w = (const float*)d_in[7];
    const float* proj_b = (const float*)d_in[8];
    const float* ffn1_w = (const float*)d_in[9];
    const float* ffn1_b = (const float*)d_in[10];
    const float* ffn2_w = (const float*)d_in[11];
    const float* ffn2_b = (const float*)d_in[12];
    float* out = (float*)d_out;

    // layout: [w1b 512K][w2b 512K][ygt 8M][scratch: s_mean/sig/Qt/Kt/Vb]
    u16* w1b = (u16*)d_ws;
    u16* w2b = w1b + 262144;
    u16* ygt = w2b + 262144;                         // [b*1024][256] bf16
    u16* scratch = ygt + (size_t)BB * NP * CC;
    float* s_mean = (float*)scratch;                 // 16 KB
    float* sig    = s_mean + BB * CC;                // 16 KB
    u16* Qt = (u16*)(sig + BB * CC);                 // 1 MB
    u16* Kt = Qt + (size_t)BB * NP * 32;             // 1 MB
    u16* Vb = Kt + (size_t)BB * NP * 32;             // 1 MB

    se_mean_conv_kernel<<<BB * CC + 512, 256, 0, stream>>>(x, s_mean, ffn1_w, w1b, ffn2_w, w2b);
    se_mlp_kernel<<<BB, 256, 0, stream>>>(s_mean, fc1_w, fc1_b, fc2_w, fc2_b, sig);
    scale_transpose_qkv_kernel<<<dim3(16, 4, BB), 256, 0, stream>>>(
        x, sig, qkv_w, qkv_b, ygt, Qt, Kt, Vb);
    attn_mfma_kernel<<<BB * 64, 256, 0, stream>>>(Qt, Kt, Vb, proj_w, proj_b, ygt);

    // fused FFN: out = ffn2_w @ relu(ffn1_w @ y + b1) + b2, h never touches HBM
    ffn_fused_kernel<<<256, 512, 0, stream>>>(w1b, w2b, ygt, ffn1_b, ffn2_b, out);
}

// Round 8
// 160.675 us; speedup vs baseline: 1.1034x; 1.1034x over previous
//
#include <hip/hip_runtime.h>
#include <cstdint>
#include <cstddef>

#define BB 16
#define CC 256
#define NP 1024   // H*W

typedef __attribute__((ext_vector_type(8))) short bf16x8;
typedef __attribute__((ext_vector_type(4))) float f32x4;
typedef unsigned short u16;

__device__ __forceinline__ u16 f2bf(float f) {
    union { float f; uint32_t u; } v; v.f = f;
    uint32_t u = v.u;
    return (u16)((u + 0x7FFFu + ((u >> 16) & 1u)) >> 16);   // RNE
}

// ---------------- SE mean (blocks 0..4095) + weight convert (blocks 4096..4607) ----------------
__global__ __launch_bounds__(256)
void se_mean_conv_kernel(const float* __restrict__ x, float* __restrict__ s_mean,
                         const float* __restrict__ w1, u16* __restrict__ d1,
                         const float* __restrict__ w2, u16* __restrict__ d2) {
    int blk = blockIdx.x;
    int t = threadIdx.x;
    if (blk < BB * CC) {
        const float* p = x + (size_t)blk * NP;
        float4 v = *(const float4*)(p + t * 4);
        float s = (v.x + v.y) + (v.z + v.w);
#pragma unroll
        for (int off = 32; off; off >>= 1) s += __shfl_down(s, off, 64);
        __shared__ float red[4];
        if ((t & 63) == 0) red[t >> 6] = s;
        __syncthreads();
        if (t == 0) s_mean[blk] = (red[0] + red[1] + red[2] + red[3]) * (1.0f / NP);
    } else {
        int blk2 = blk - BB * CC;
        const float* src = (blk2 < 256) ? w1 : w2;
        u16* dst = (blk2 < 256) ? d1 : d2;
        int i = ((blk2 & 255) * 256 + t) * 4;
        float4 v = *(const float4*)(src + i);
        ushort4 o;
        o.x = f2bf(v.x); o.y = f2bf(v.y); o.z = f2bf(v.z); o.w = f2bf(v.w);
        *(ushort4*)(dst + i) = o;
    }
}

// ---------------- SE MLP: sigmoid scales, once per batch (grid = BB) ----------------
__global__ __launch_bounds__(256)
void se_mlp_kernel(const float* __restrict__ s_mean,
                   const float* __restrict__ fc1_w, const float* __restrict__ fc1_b,
                   const float* __restrict__ fc2_w, const float* __restrict__ fc2_b,
                   float* __restrict__ sig) {
    int b = blockIdx.x, t = threadIdx.x;
    __shared__ float sm[256];
    __shared__ float part[4][64];
    __shared__ float h1[64];
    sm[t] = s_mean[b * 256 + t];
    __syncthreads();
    int to = t & 63, g = t >> 6;
    float a = 0.f;
#pragma unroll 8
    for (int c = 0; c < 64; ++c) a += fc1_w[to * 256 + g * 64 + c] * sm[g * 64 + c];
    part[g][to] = a;
    __syncthreads();
    if (t < 64) h1[t] = fmaxf(part[0][t] + part[1][t] + part[2][t] + part[3][t] + fc1_b[t], 0.f);
    __syncthreads();
    float acc = fc2_b[t];
#pragma unroll 8
    for (int j = 0; j < 64; ++j) acc += fc2_w[t * 64 + j] * h1[j];
    sig[b * 256 + t] = 1.f / (1.f + __expf(-acc));
}

// ---- scale + transpose (+ fused qkv on ct==0 blocks); SE scales precomputed ----
__global__ __launch_bounds__(256)
void scale_transpose_qkv_kernel(const float* __restrict__ x, const float* __restrict__ sig,
                                const float* __restrict__ qW, const float* __restrict__ qB,
                                u16* __restrict__ ygt, u16* __restrict__ Qt,
                                u16* __restrict__ Kt, u16* __restrict__ Vb) {
    // grid: (16 nt, 4 ct, BB)
    int nt = blockIdx.x, ct = blockIdx.y, b = blockIdx.z;
    __shared__ float tile[64][65];
    __shared__ float ws[64 * 32];
    __shared__ float bs[64];
    __shared__ float vtile[32][64];
    __shared__ float sig_l[64];
    int t = threadIdx.x;
    const float* Xb = x + ((size_t)b * CC + ct * 64) * NP + nt * 64;
    if (t < 64) sig_l[t] = sig[b * 256 + ct * 64 + t];
    if (ct == 0) {
        for (int e = t; e < 2048; e += 256) ws[e] = qW[e];
        if (t < 64) bs[t] = qB[t];
    }
#pragma unroll
    for (int p = 0; p < 4; ++p) {
        int e = t + p * 256;
        int c = e >> 4, n4 = (e & 15) * 4;
        float4 v = *(const float4*)&Xb[(size_t)c * NP + n4];
        tile[c][n4] = v.x; tile[c][n4 + 1] = v.y; tile[c][n4 + 2] = v.z; tile[c][n4 + 3] = v.w;
    }
    __syncthreads();
    u16* Yb = ygt + ((size_t)b * NP + nt * 64) * CC + ct * 64;
#pragma unroll
    for (int p = 0; p < 4; ++p) {
        int e = t + p * 256;
        int n = e >> 4, c4 = (e & 15) * 4;
        if (ct * 64 + c4 >= 32) {
            ushort4 o;
            o.x = f2bf(tile[c4][n] * sig_l[c4]);
            o.y = f2bf(tile[c4 + 1][n] * sig_l[c4 + 1]);
            o.z = f2bf(tile[c4 + 2][n] * sig_l[c4 + 2]);
            o.w = f2bf(tile[c4 + 3][n] * sig_l[c4 + 3]);
            *(ushort4*)&Yb[(size_t)n * CC + c4] = o;
        }
    }
    if (ct == 0) {
        int nn = t & 63, g = t >> 6;
        int n = nt * 64 + nn;
        float xs[32];
#pragma unroll
        for (int c = 0; c < 32; ++c) xs[c] = tile[c][nn] * sig_l[c];
        float acc[16];
#pragma unroll
        for (int oc = 0; oc < 16; ++oc) {
            int o = g * 16 + oc;
            float a = bs[o];
#pragma unroll
            for (int c = 0; c < 32; ++c) a += ws[o * 32 + c] * xs[c];
            acc[oc] = a;
        }
        if (g == 0) {
            u16* qr = Qt + ((size_t)b * NP + n) * 32;
            ushort4 z4; z4.x = 0; z4.y = 0; z4.z = 0; z4.w = 0;
#pragma unroll
            for (int j = 0; j < 16; j += 4) {
                ushort4 o4;
                o4.x = f2bf(acc[j] * 0.25f);     o4.y = f2bf(acc[j + 1] * 0.25f);
                o4.z = f2bf(acc[j + 2] * 0.25f); o4.w = f2bf(acc[j + 3] * 0.25f);
                *(ushort4*)&qr[j] = o4;
            }
            *(ushort4*)&qr[16] = z4; *(ushort4*)&qr[20] = z4;
            *(ushort4*)&qr[24] = z4; *(ushort4*)&qr[28] = z4;
        } else if (g == 1) {
            u16* kr = Kt + ((size_t)b * NP + n) * 32;
            ushort4 z4; z4.x = 0; z4.y = 0; z4.z = 0; z4.w = 0;
#pragma unroll
            for (int j = 0; j < 16; j += 4) {
                ushort4 k4;
                k4.x = f2bf(acc[j]);     k4.y = f2bf(acc[j + 1]);
                k4.z = f2bf(acc[j + 2]); k4.w = f2bf(acc[j + 3]);
                *(ushort4*)&kr[j] = k4;
            }
            *(ushort4*)&kr[16] = z4; *(ushort4*)&kr[20] = z4;
            *(ushort4*)&kr[24] = z4; *(ushort4*)&kr[28] = z4;
        } else {
#pragma unroll
            for (int oc = 0; oc < 16; ++oc) vtile[(g - 2) * 16 + oc][nn] = acc[oc];
        }
        __syncthreads();
        for (int e = t; e < 2048; e += 256) {
            int c = e >> 6, nn2 = e & 63;
            Vb[(size_t)b * 32 * NP + (size_t)c * NP + nt * 64 + nn2] = f2bf(vtile[c][nn2]);
        }
    }
}

// ---------------- MFMA flash attention + fused proj (parallel epilogue) ----------------
__global__ __launch_bounds__(256)
void attn_mfma_kernel(const u16* __restrict__ Qt, const u16* __restrict__ Kt,
                      const u16* __restrict__ Vb,
                      const float* __restrict__ proj_w, const float* __restrict__ proj_b,
                      u16* __restrict__ ygt) {
    int b = blockIdx.x & 15;
    int n0 = (blockIdx.x >> 4) * 16;
    __shared__ __align__(16) u16 P_lds[4][16][40];
    __shared__ float al_lds[4][16];
    __shared__ float sm_lds[4][16];
    __shared__ float sl_lds[4][16];
    __shared__ float O_lds[4][16][33];
    __shared__ float pw_s[32][33];   // +1 pad: proj reads conflict-free
    __shared__ float pb_s[32];
    int t = threadIdx.x;
    int w = t >> 6, lane = t & 63;
    int q = lane >> 4, idx = lane & 15;

    for (int e = t; e < 1024; e += 256) pw_s[e >> 5][e & 31] = proj_w[e];
    if (t < 32) pb_s[t] = proj_b[t];
    __syncthreads();

    const u16* Qb = Qt + (size_t)b * NP * 32;
    const u16* Kb = Kt + (size_t)b * NP * 32;
    const u16* Vp = Vb + (size_t)b * 32 * NP;

    int nrow = n0 + idx;
    bf16x8 aq = *(const bf16x8*)&Qb[(size_t)nrow * 32 + q * 8];

    f32x4 O0 = {0.f, 0.f, 0.f, 0.f}, O1 = {0.f, 0.f, 0.f, 0.f};
    float m_run[4] = {-1e30f, -1e30f, -1e30f, -1e30f};
    float l_run[4] = {0.f, 0.f, 0.f, 0.f};

    int mbase = w * 256;
    for (int m0 = mbase; m0 < mbase + 256; m0 += 32) {
        bf16x8 bk0 = *(const bf16x8*)&Kb[(size_t)(m0 + idx) * 32 + q * 8];
        bf16x8 bk1 = *(const bf16x8*)&Kb[(size_t)(m0 + 16 + idx) * 32 + q * 8];
        bf16x8 va0 = *(const bf16x8*)&Vp[(size_t)idx * NP + m0 + q * 8];
        bf16x8 va1 = *(const bf16x8*)&Vp[(size_t)(16 + idx) * NP + m0 + q * 8];
        f32x4 z = {0.f, 0.f, 0.f, 0.f};
        f32x4 S0 = __builtin_amdgcn_mfma_f32_16x16x32_bf16(aq, bk0, z, 0, 0, 0);
        f32x4 S1 = __builtin_amdgcn_mfma_f32_16x16x32_bf16(aq, bk1, z, 0, 0, 0);
        float mx[4], p0[4], p1[4], alpha[4];
#pragma unroll
        for (int r = 0; r < 4; ++r) mx[r] = fmaxf(S0[r], S1[r]);
#pragma unroll
        for (int off = 1; off < 16; off <<= 1)
#pragma unroll
            for (int r = 0; r < 4; ++r) mx[r] = fmaxf(mx[r], __shfl_xor(mx[r], off, 64));
#pragma unroll
        for (int r = 0; r < 4; ++r) {
            float nm = fmaxf(m_run[r], mx[r]);
            alpha[r] = __expf(m_run[r] - nm);
            m_run[r] = nm;
            p0[r] = __expf(S0[r] - nm);
            p1[r] = __expf(S1[r] - nm);
        }
#pragma unroll
        for (int r = 0; r < 4; ++r) {
            float s = p0[r] + p1[r];
#pragma unroll
            for (int off = 1; off < 16; off <<= 1) s += __shfl_xor(s, off, 64);
            l_run[r] = l_run[r] * alpha[r] + s;
        }
#pragma unroll
        for (int r = 0; r < 4; ++r) {
            P_lds[w][q * 4 + r][idx]      = f2bf(p0[r]);
            P_lds[w][q * 4 + r][idx + 16] = f2bf(p1[r]);
        }
        if (idx == 0) {
#pragma unroll
            for (int r = 0; r < 4; ++r) al_lds[w][q * 4 + r] = alpha[r];
        }
        float an = al_lds[w][idx];
#pragma unroll
        for (int r = 0; r < 4; ++r) { O0[r] *= an; O1[r] *= an; }
        bf16x8 pf = *(const bf16x8*)&P_lds[w][idx][q * 8];
        O0 = __builtin_amdgcn_mfma_f32_16x16x32_bf16(va0, pf, O0, 0, 0, 0);
        O1 = __builtin_amdgcn_mfma_f32_16x16x32_bf16(va1, pf, O1, 0, 0, 0);
    }
    if (idx == 0) {
#pragma unroll
        for (int r = 0; r < 4; ++r) {
            sm_lds[w][q * 4 + r] = m_run[r];
            sl_lds[w][q * 4 + r] = l_run[r];
        }
    }
#pragma unroll
    for (int r = 0; r < 4; ++r) {
        O_lds[w][idx][q * 4 + r]      = O0[r];
        O_lds[w][idx][q * 4 + r + 16] = O1[r];
    }
    __syncthreads();

    // ---- Phase 1: combine 4 wave-partials (all 256 threads, 2 elements each) ----
#pragma unroll
    for (int p = 0; p < 2; ++p) {
        int el = t + p * 256;
        int row = el >> 5, col = el & 31;
        float m0_ = sm_lds[0][row], m1 = sm_lds[1][row], m2 = sm_lds[2][row], m3 = sm_lds[3][row];
        float gm = fmaxf(fmaxf(m0_, m1), fmaxf(m2, m3));
        float e0 = __expf(m0_ - gm), e1 = __expf(m1 - gm);
        float e2 = __expf(m2 - gm), e3 = __expf(m3 - gm);
        float linv = 1.f / (sl_lds[0][row] * e0 + sl_lds[1][row] * e1 +
                            sl_lds[2][row] * e2 + sl_lds[3][row] * e3);
        O_lds[0][row][col] = (O_lds[0][row][col] * e0 + O_lds[1][row][col] * e1 +
                              O_lds[2][row][col] * e2 + O_lds[3][row][col] * e3) * linv;
    }
    __syncthreads();

    // ---- Phase 2: proj across all 4 waves: wave w owns rows w*4..+4 ----
    {
        int row = (w << 2) + q;
        float o0 = pb_s[idx], o1 = pb_s[idx + 16];
#pragma unroll
        for (int c = 0; c < 32; ++c) {
            float xv = O_lds[0][row][c];
            o0 += pw_s[idx][c] * xv;
            o1 += pw_s[idx + 16][c] * xv;
        }
        u16* yrow = ygt + ((size_t)b * NP + n0 + row) * CC;
        yrow[idx]      = f2bf(o0);
        yrow[idx + 16] = f2bf(o1);
    }
}

// ---------------- Fused FFN v3 (verbatim 162.7-us config) ----------------
// 64 px/block, 8 waves, async LDS weight staging. Superchunk = 128 h rows.
// stage1: wave w computes h rows w*16 (K=256 from Ys LDS, W1 in regs).
// stage2: wave w accumulates out rows (w&3)*64 over k-half (w>>2), W2 slice async-staged in LDS.
// Cross-pair (w, w+4) reduction through the dead W2s region at the end.
// NOTE: 2x reg-blocked stage1 refuted 3x (v5/v6/v7): allocator will not hold a second
// 64-VGPR fragment set next to oacc[4][4]; loads sink -> exposed L2 latency. Do not retry.
__global__ __launch_bounds__(512, 2)
void ffn_fused_kernel(const u16* __restrict__ w1b, const u16* __restrict__ w2b,
                      const u16* __restrict__ ygt,
                      const float* __restrict__ bias1, const float* __restrict__ bias2,
                      float* __restrict__ out) {
    __shared__ __align__(16) u16 Ys[4][64][64];     // 32 KB: y tile [kb][n][64k swz]
    __shared__ __align__(16) u16 Hs[2][64][64];     // 16 KB: h superchunk [hh][n][64m swz]
    __shared__ __align__(16) u16 W2s[2][256][64];   // 64 KB: W2 slice [hh][m2][64k swz]
    __shared__ float Bs1[1024];                     // 4 KB
    int t = threadIdx.x;
    int w = t >> 6, lane = t & 63;
    int q = lane >> 4, idx = lane & 15;
    int srow = lane >> 3;            // 0..7
    int gch = (lane & 7) ^ srow;     // pre-swizzled source chunk
    int n0 = blockIdx.x * 64;        // flat pixel base (b*1024 + n)
    int rot = blockIdx.x & 7;
    int hh = w >> 2, wm = w & 3;

#define ISSUE_W2S(sc_)                                                                     \
    {                                                                                      \
        _Pragma("unroll")                                                                  \
        for (int e = 0; e < 8; ++e) {                                                      \
            int hh2 = e >> 2, rnd = e & 3;                                                 \
            int rw = rnd * 64 + w * 8;                                                     \
            __builtin_amdgcn_global_load_lds(                                              \
                (const __attribute__((address_space(1))) void*)(w2b + (size_t)(rw + srow) * 1024 + (sc_) * 128 + hh2 * 64 + gch * 8), \
                (__attribute__((address_space(3))) void*)(&W2s[hh2][rw][0]),               \
                16, 0, 0);                                                                 \
        }                                                                                  \
    }

#define LOAD_AF(dst, sc_)                                                                  \
    {                                                                                      \
        const u16* a1 = w1b + ((size_t)((sc_) * 128 + w * 16 + idx)) * CC;                 \
        _Pragma("unroll")                                                                  \
        for (int s = 0; s < 8; ++s) dst[s] = *(const bf16x8*)(a1 + s * 32 + q * 8);        \
    }

    // stage Ys: 256 rows of 128 B, linear LDS dest + pre-swizzled source
#pragma unroll
    for (int e = 0; e < 4; ++e) {
        __builtin_amdgcn_global_load_lds(
            (const __attribute__((address_space(1))) void*)(ygt + (size_t)(n0 + w * 8 + srow) * CC + e * 64 + gch * 8),
            (__attribute__((address_space(3))) void*)(&Ys[e][w * 8][0]),
            16, 0, 0);
    }
    Bs1[t] = bias1[t];
    Bs1[t + 512] = bias1[t + 512];

    f32x4 oacc[4][4];
#pragma unroll
    for (int f = 0; f < 4; ++f)
#pragma unroll
        for (int j = 0; j < 4; ++j) { f32x4 z = {0.f, 0.f, 0.f, 0.f}; oacc[f][j] = z; }

    ISSUE_W2S(rot)
    bf16x8 af[8];
    LOAD_AF(af, rot)
    __syncthreads();   // drains Ys + W2s(first); af waits resolve at first MFMA use

    for (int it = 0; it < 8; ++it) {
        int sc  = (it + rot) & 7;
        int scn = (it + 1 + rot) & 7;
        // prefetch next W1 frags early: hides L2 latency under stage-1 MFMAs
        bf16x8 afn[8];
        if (it + 1 < 8) LOAD_AF(afn, scn)

        // stage 1: h[16m x 64n] per wave, K=256 from Ys
        f32x4 hacc[4];
#pragma unroll
        for (int j = 0; j < 4; ++j) { f32x4 z = {0.f, 0.f, 0.f, 0.f}; hacc[j] = z; }
#pragma unroll
        for (int s = 0; s < 8; ++s) {
            int kb = s >> 1, h2 = s & 1;
#pragma unroll
            for (int j = 0; j < 4; ++j) {
                bf16x8 yb = *(const bf16x8*)&Ys[kb][j * 16 + idx][(((q + 4 * h2) ^ (idx & 7)) * 8)];
                hacc[j] = __builtin_amdgcn_mfma_f32_16x16x32_bf16(af[s], yb, hacc[j], 0, 0, 0);
            }
        }

        // bias + relu + pack -> Hs[hh]; m in its 64-slice = wm*16 + q*4 + r, row n = j*16+idx
        int mb = sc * 128 + w * 16 + q * 4;
        float b0 = Bs1[mb], b1v = Bs1[mb + 1], b2v = Bs1[mb + 2], b3v = Bs1[mb + 3];
        int chk_hi = wm * 2 + (q >> 1);
#pragma unroll
        for (int j = 0; j < 4; ++j) {
            int n = j * 16 + idx;
            int chk = chk_hi ^ (n & 7);
            uint32_t lo = (uint32_t)f2bf(fmaxf(hacc[j][0] + b0, 0.f)) |
                          ((uint32_t)f2bf(fmaxf(hacc[j][1] + b1v, 0.f)) << 16);
            uint32_t hi = (uint32_t)f2bf(fmaxf(hacc[j][2] + b2v, 0.f)) |
                          ((uint32_t)f2bf(fmaxf(hacc[j][3] + b3v, 0.f)) << 16);
            uint32_t* hp = (uint32_t*)&Hs[hh][n][chk * 8 + (q & 1) * 4];
            hp[0] = lo; hp[1] = hi;
        }
        __syncthreads();   // B: Hs visible + W2s(sc) DMA drained

        // stage 2: oacc[64m2 x 64n] += W2s[hh] @ Hs[hh] (wave's own k-half)
#pragma unroll
        for (int s2 = 0; s2 < 2; ++s2) {
            bf16x8 a2f[4];
#pragma unroll
            for (int f = 0; f < 4; ++f)
                a2f[f] = *(const bf16x8*)&W2s[hh][wm * 64 + f * 16 + idx][(((q + 4 * s2) ^ (idx & 7)) * 8)];
#pragma unroll
            for (int j = 0; j < 4; ++j) {
                bf16x8 hb = *(const bf16x8*)&Hs[hh][j * 16 + idx][(((q + 4 * s2) ^ (idx & 7)) * 8)];
#pragma unroll
                for (int f = 0; f < 4; ++f)
                    oacc[f][j] = __builtin_amdgcn_mfma_f32_16x16x32_bf16(a2f[f], hb, oacc[f][j], 0, 0, 0);
            }
        }
        __syncthreads();   // C: all waves done reading W2s/Hs -> safe to overwrite

        if (it + 1 < 8) {
            ISSUE_W2S(scn)
#pragma unroll
            for (int s = 0; s < 8; ++s) af[s] = afn[s];
        }
    }
#undef ISSUE_W2S
#undef LOAD_AF

    // cross-pair reduction through the dead W2s region (64 KB = 4 pairs x 16 KB f32)
    float* R = (float*)&W2s[0][0][0];
    if (w >= 4) {
#pragma unroll
        for (int f = 0; f < 4; ++f)
#pragma unroll
            for (int j = 0; j < 4; ++j)
#pragma unroll
                for (int r = 0; r < 4; ++r)
                    R[(wm * 64 + f * 16 + q * 4 + r) * 64 + j * 16 + idx] = oacc[f][j][r];
    }
    __syncthreads();
    if (w < 4) {
        int b = n0 >> 10, nnb = n0 & 1023;
#pragma unroll
        for (int f = 0; f < 4; ++f) {
            int m2 = wm * 64 + f * 16 + q * 4;
            float c0 = bias2[m2], c1 = bias2[m2 + 1], c2 = bias2[m2 + 2], c3 = bias2[m2 + 3];
#pragma unroll
            for (int j = 0; j < 4; ++j) {
                int col = j * 16 + idx;
                const float* Rp = &R[m2 * 64 + col];
                float* p = out + ((size_t)b * CC + m2) * NP + nnb + col;
                f32x4 v = oacc[f][j];
                p[0]      = v.x + c0 + Rp[0];
                p[NP]     = v.y + c1 + Rp[64];
                p[2 * NP] = v.z + c2 + Rp[128];
                p[3 * NP] = v.w + c3 + Rp[192];
            }
        }
    }
}

extern "C" void kernel_launch(void* const* d_in, const int* in_sizes, int n_in,
                              void* d_out, int out_size, void* d_ws, size_t ws_size,
                              hipStream_t stream) {
    const float* x      = (const float*)d_in[0];
    const float* fc1_w  = (const float*)d_in[1];
    const float* fc1_b  = (const float*)d_in[2];
    const float* fc2_w  = (const float*)d_in[3];
    const float* fc2_b  = (const float*)d_in[4];
    const float* qkv_w  = (const float*)d_in[5];
    const float* qkv_b  = (const float*)d_in[6];
    const float* proj_w = (const float*)d_in[7];
    const float* proj_b = (const float*)d_in[8];
    const float* ffn1_w = (const float*)d_in[9];
    const float* ffn1_b = (const float*)d_in[10];
    const float* ffn2_w = (const float*)d_in[11];
    const float* ffn2_b = (const float*)d_in[12];
    float* out = (float*)d_out;

    // layout: [w1b 512K][w2b 512K][ygt 8M][scratch: s_mean/sig/Qt/Kt/Vb]
    u16* w1b = (u16*)d_ws;
    u16* w2b = w1b + 262144;
    u16* ygt = w2b + 262144;                         // [b*1024][256] bf16
    u16* scratch = ygt + (size_t)BB * NP * CC;
    float* s_mean = (float*)scratch;                 // 16 KB
    float* sig    = s_mean + BB * CC;                // 16 KB
    u16* Qt = (u16*)(sig + BB * CC);                 // 1 MB
    u16* Kt = Qt + (size_t)BB * NP * 32;             // 1 MB
    u16* Vb = Kt + (size_t)BB * NP * 32;             // 1 MB

    se_mean_conv_kernel<<<BB * CC + 512, 256, 0, stream>>>(x, s_mean, ffn1_w, w1b, ffn2_w, w2b);
    se_mlp_kernel<<<BB, 256, 0, stream>>>(s_mean, fc1_w, fc1_b, fc2_w, fc2_b, sig);
    scale_transpose_qkv_kernel<<<dim3(16, 4, BB), 256, 0, stream>>>(
        x, sig, qkv_w, qkv_b, ygt, Qt, Kt, Vb);
    attn_mfma_kernel<<<BB * 64, 256, 0, stream>>>(Qt, Kt, Vb, proj_w, proj_b, ygt);

    // fused FFN: out = ffn2_w @ relu(ffn1_w @ y + b1) + b2, h never touches HBM
    ffn_fused_kernel<<<256, 512, 0, stream>>>(w1b, w2b, ygt, ffn1_b, ffn2_b, out);
}